// Round 3
// baseline (2074.688 us; speedup 1.0000x reference)
//
#include <hip/hip_runtime.h>
#include <hip/hip_bf16.h>
#include <math.h>

#define BT 32768        // B*T tokens
#define HH 1024

typedef unsigned short u16;
typedef __attribute__((ext_vector_type(4))) unsigned short u16x4;
typedef __attribute__((ext_vector_type(8))) __bf16 bf16x8;
typedef __attribute__((ext_vector_type(4))) float f32x4;

#define DEVI static __device__ __forceinline__

DEVI u16 f2bf(float f){
  unsigned u = __builtin_bit_cast(unsigned, f);
  u += 0x7FFFu + ((u >> 16) & 1u);
  return (u16)(u >> 16);
}
DEVI float bf2f(u16 h){
  unsigned u = ((unsigned)h) << 16;
  return __builtin_bit_cast(float, u);
}
DEVI void gl_lds16(const void* g, void* l){
  __builtin_amdgcn_global_load_lds((const __attribute__((address_space(1))) void*)g,
                                   (__attribute__((address_space(3))) void*)l, 16, 0, 0);
}
// T2 swizzle: 16B-granule XOR within a 64-elem (128B) row. elem units of u16.
DEVI int swz(int row, int elem){ return elem ^ ((row & 7) << 3); }

// ---------------- elementwise prep kernels ----------------
__global__ void k_cast4(const float* __restrict__ s, u16* __restrict__ d, int n4){
  int i = blockIdx.x*blockDim.x + threadIdx.x;
  int st = gridDim.x*blockDim.x;
  for (; i < n4; i += st){
    float4 v = ((const float4*)s)[i];
    u16x4 o = { f2bf(v.x), f2bf(v.y), f2bf(v.z), f2bf(v.w) };
    ((u16x4*)d)[i] = o;
  }
}

// x2 -> stacked slot 2 (ld 3072)
__global__ void k_pack_x2(const float* __restrict__ s, u16* __restrict__ d, int n4){
  int i = blockIdx.x*blockDim.x + threadIdx.x;
  int st = gridDim.x*blockDim.x;
  for (; i < n4; i += st){
    int e = i*4; int t = e >> 10; int c = e & 1023;
    float4 v = *(const float4*)&s[e];
    u16x4 o = { f2bf(v.x), f2bf(v.y), f2bf(v.z), f2bf(v.w) };
    *(u16x4*)&d[(size_t)t*3072 + 2048 + c] = o;
  }
}

// qb = bf16(query_token + static_context)
__global__ void k_qb(const float* __restrict__ qt, const float* __restrict__ sc,
                     u16* __restrict__ d, int n4){
  int i = blockIdx.x*blockDim.x + threadIdx.x;
  int st = gridDim.x*blockDim.x;
  for (; i < n4; i += st){
    int e = i*4; int c = e & 1023;
    float4 v = *(const float4*)&sc[e];
    float4 q = *(const float4*)&qt[c];
    u16x4 o = { f2bf(v.x+q.x), f2bf(v.y+q.y), f2bf(v.z+q.z), f2bf(v.w+q.w) };
    ((u16x4*)d)[i] = o;
  }
}

__global__ void k_copyf(const float* __restrict__ s, float* __restrict__ d, int n){
  int i = blockIdx.x*blockDim.x + threadIdx.x;
  int st = gridDim.x*blockDim.x;
  for (; i < n; i += st) d[i] = s[i];
}

// ---------------- 256x256 GEMM, BK=64, 8 waves, counted-vmcnt pipeline ----------------
// C[M,N](bf16) = A[M,K](bf16) @ B[N,K]^T + bias, opt gelu. dbuf LDS (128KB),
// next K-tile's global_load_lds stay in flight across the barrier (vmcnt(8), never 0
// in-loop). Raw s_barrier + memory-clobber asm pin ordering (guide rule #18/#21).
__global__ __launch_bounds__(512, 2)
void k_gemm256(const u16* __restrict__ A, int lda,
               const u16* __restrict__ B, int ldb, int K,
               const float* __restrict__ bias,
               u16* __restrict__ C, int ldc, int col0, int act)
{
  __shared__ u16 As[2][256*64];
  __shared__ u16 Bs[2][256*64];
  const int tid = threadIdx.x, lane = tid & 63;
  const int wid = tid >> 6;
  const int wr = wid >> 2, wc = wid & 3;     // 2 x 4 waves -> per-wave 128x64 output
  const int r15 = lane & 15, g = lane >> 4;
  const int m0 = blockIdx.x * 256, n0 = blockIdx.y * 256;
  f32x4 acc[8][4] = {};

  const int srow = tid >> 3;            // 0..63
  const int scol = (tid & 7) * 8;       // 0..56  (16B granule)

  auto stage = [&](int t, int b){
    const int k0 = t * 64;
    #pragma unroll
    for (int r = 0; r < 4; ++r){
      int row = r*64 + srow;
      int ke = swz(row, scol);          // inverse-swizzled global source, linear LDS dest
      gl_lds16(A + (size_t)(m0+row)*lda + (k0+ke), &As[b][row*64 + scol]);
    }
    #pragma unroll
    for (int r = 0; r < 4; ++r){
      int row = r*64 + srow;
      int ke = swz(row, scol);
      gl_lds16(B + (size_t)(n0+row)*ldb + (k0+ke), &Bs[b][row*64 + scol]);
    }
  };

  auto compute = [&](int b){
    __builtin_amdgcn_s_setprio(1);
    #pragma unroll
    for (int kk = 0; kk < 64; kk += 32){
      bf16x8 av[8], bv[4];
      #pragma unroll
      for (int i = 0; i < 8; ++i){
        int row = wr*128 + i*16 + r15;
        av[i] = *(const bf16x8*)&As[b][row*64 + swz(row, kk + g*8)];
      }
      #pragma unroll
      for (int j = 0; j < 4; ++j){
        int row = wc*64 + j*16 + r15;
        bv[j] = *(const bf16x8*)&Bs[b][row*64 + swz(row, kk + g*8)];
      }
      #pragma unroll
      for (int i = 0; i < 8; ++i)
        #pragma unroll
        for (int j = 0; j < 4; ++j)
          acc[i][j] = __builtin_amdgcn_mfma_f32_16x16x32_bf16(av[i], bv[j], acc[i][j], 0, 0, 0);
    }
    __builtin_amdgcn_s_setprio(0);
  };

  const int nt = K >> 6;
  stage(0, 0);
  for (int t = 0; t < nt-1; ++t){
    stage(t+1, (t+1)&1);                          // 8 loads in flight across barrier
    asm volatile("s_waitcnt vmcnt(8)" ::: "memory");  // tile t complete, t+1 in flight
    __builtin_amdgcn_s_barrier();
    asm volatile("" ::: "memory");
    compute(t&1);
    asm volatile("" ::: "memory");
    __builtin_amdgcn_s_barrier();                 // all reads of buf[t&1] done
    asm volatile("" ::: "memory");
  }
  asm volatile("s_waitcnt vmcnt(0)" ::: "memory");
  __builtin_amdgcn_s_barrier();
  asm volatile("" ::: "memory");
  compute((nt-1)&1);

  #pragma unroll
  for (int j = 0; j < 4; ++j){
    int col = wc*64 + j*16 + r15;
    float bb = bias ? bias[n0 + col] : 0.f;
    #pragma unroll
    for (int i = 0; i < 8; ++i){
      #pragma unroll
      for (int jj = 0; jj < 4; ++jj){
        int row = wr*128 + i*16 + g*4 + jj;
        float v = acc[i][j][jj] + bb;
        if (act == 1) v = 0.5f * v * (1.f + erff(v * 0.70710678118654752f));
        C[(size_t)(m0+row)*ldc + col0 + n0 + col] = f2bf(v);
      }
    }
  }
}

// ---------------- fused K/V projection + M=3 cross-attention ----------------
// block: 32 tokens (96 stacked rows) x 128 cols (2 heads). K,V GEMM tiles in regs,
// then scores -> softmax over 3 modalities -> ctx + head-mean weights in epilogue.
// grid: (bn fast, bt slow) so the 8 column-blocks sharing an A-panel run concurrently
// across XCDs -> L3 serves the re-reads (T1-style locality).
__global__ __launch_bounds__(256, 3)
void k_attn(const u16* __restrict__ S, const u16* __restrict__ Wk, const u16* __restrict__ Wv,
            const float* __restrict__ bk, const float* __restrict__ bv,
            const u16* __restrict__ Q, u16* __restrict__ ctx, float* __restrict__ wacc)
{
  __shared__ __align__(16) char smem[45056];
  u16* As  = (u16*)smem;                    // 96x64
  u16* Bk  = (u16*)(smem + 12288);          // 128x64
  u16* Bv  = (u16*)(smem + 12288 + 16384);  // 128x64
  u16* Vl  = (u16*)smem;                    // epilogue: 96x128 bf16
  u16* Ql  = (u16*)(smem + 24576);          // epilogue: 32x128 bf16
  float* Sl = (float*)(smem + 24576 + 8192);// epilogue: 2 heads x 96 rows

  const int tid = threadIdx.x, lane = tid & 63, wid = tid >> 6;
  const int wr = wid >> 1, wcH = wid & 1;
  const int r15 = lane & 15, g = lane >> 4;
  const int bn = blockIdx.x, bt = blockIdx.y;
  const int row0 = bt * 96, n0 = bn * 128;

  f32x4 aK[3][4] = {}; f32x4 aV[3][4] = {};

  for (int k0 = 0; k0 < 1024; k0 += 64){
    #pragma unroll
    for (int it = 0; it < 3; ++it){
      int c = it*256 + tid; int row = c >> 3;
      int ke = swz(row, (c & 7) * 8);
      gl_lds16(S + (size_t)(row0+row)*1024 + k0 + ke, As + c*8);
    }
    #pragma unroll
    for (int it = 0; it < 4; ++it){
      int c = it*256 + tid; int row = c >> 3;
      int ke = swz(row, (c & 7) * 8);
      gl_lds16(Wk + (size_t)(n0+row)*1024 + k0 + ke, Bk + c*8);
      gl_lds16(Wv + (size_t)(n0+row)*1024 + k0 + ke, Bv + c*8);
    }
    __syncthreads();
    #pragma unroll
    for (int kk = 0; kk < 64; kk += 32){
      bf16x8 av[3], b1[4], b2[4];
      #pragma unroll
      for (int i = 0; i < 3; ++i){
        int row = wr*48 + i*16 + r15;
        av[i] = *(const bf16x8*)&As[row*64 + swz(row, kk + g*8)];
      }
      #pragma unroll
      for (int j = 0; j < 4; ++j){
        int row = wcH*64 + j*16 + r15;
        b1[j] = *(const bf16x8*)&Bk[row*64 + swz(row, kk + g*8)];
        b2[j] = *(const bf16x8*)&Bv[row*64 + swz(row, kk + g*8)];
      }
      #pragma unroll
      for (int i = 0; i < 3; ++i)
        #pragma unroll
        for (int j = 0; j < 4; ++j){
          aK[i][j] = __builtin_amdgcn_mfma_f32_16x16x32_bf16(av[i], b1[j], aK[i][j], 0, 0, 0);
          aV[i][j] = __builtin_amdgcn_mfma_f32_16x16x32_bf16(av[i], b2[j], aV[i][j], 0, 0, 0);
        }
    }
    __syncthreads();
  }

  // V (+bias) -> LDS as bf16
  #pragma unroll
  for (int j = 0; j < 4; ++j){
    int col = wcH*64 + j*16 + r15;
    float bvv = bv[n0 + col];
    #pragma unroll
    for (int i = 0; i < 3; ++i)
      #pragma unroll
      for (int jj = 0; jj < 4; ++jj){
        int row = wr*48 + i*16 + g*4 + jj;
        Vl[row*128 + col] = f2bf(aV[i][j][jj] + bvv);
      }
  }
  // stage Q tile [32 tokens][128 cols]
  #pragma unroll
  for (int it = 0; it < 4; ++it){
    int c4 = it*256 + tid;              // 1024 chunks of 4 elems
    int tt = c4 >> 5, cc = (c4 & 31)*4;
    *(u16x4*)&Ql[tt*128 + cc] = *(const u16x4*)&Q[(size_t)(bt*32 + tt)*1024 + n0 + cc];
  }
  __syncthreads();

  // scores: s[row] = (Q[t,h,:] . (K[row,:]+bk)) / 8 ; d-reduction over 4 col-frags + 16 lanes
  float bkv[4];
  #pragma unroll
  for (int j = 0; j < 4; ++j) bkv[j] = bk[n0 + wcH*64 + j*16 + r15];
  #pragma unroll
  for (int i = 0; i < 3; ++i){
    #pragma unroll
    for (int jj = 0; jj < 4; ++jj){
      int row = wr*48 + i*16 + g*4 + jj;   // 0..95
      int tt = row / 3;
      float s = 0.f;
      #pragma unroll
      for (int j = 0; j < 4; ++j){
        float qv = bf2f(Ql[tt*128 + wcH*64 + j*16 + r15]);
        s += (aK[i][j][jj] + bkv[j]) * qv;
      }
      s += __shfl_xor(s, 1); s += __shfl_xor(s, 2);
      s += __shfl_xor(s, 4); s += __shfl_xor(s, 8);
      if (r15 == 0) Sl[wcH*96 + row] = s * 0.125f;
    }
  }
  __syncthreads();

  // softmax over m=3, ctx, head-averaged weights
  const int t0 = bt*32;
  #pragma unroll
  for (int it = 0; it < 16; ++it){
    int idx = it*256 + tid;
    int tt = idx >> 7, col = idx & 127;
    int h = col >> 6;
    float s0 = Sl[h*96 + tt*3 + 0];
    float s1 = Sl[h*96 + tt*3 + 1];
    float s2 = Sl[h*96 + tt*3 + 2];
    float mx = fmaxf(s0, fmaxf(s1, s2));
    float e0 = expf(s0-mx), e1 = expf(s1-mx), e2 = expf(s2-mx);
    float inv = 1.f/(e0+e1+e2);
    e0 *= inv; e1 *= inv; e2 *= inv;
    float c = e0*bf2f(Vl[(tt*3+0)*128 + col])
            + e1*bf2f(Vl[(tt*3+1)*128 + col])
            + e2*bf2f(Vl[(tt*3+2)*128 + col]);
    ctx[(size_t)(t0+tt)*1024 + n0 + col] = f2bf(c);
    if ((col & 63) == 0){
      atomicAdd(&wacc[(size_t)(t0+tt)*3 + 0], e0*0.0625f);
      atomicAdd(&wacc[(size_t)(t0+tt)*3 + 1], e1*0.0625f);
      atomicAdd(&wacc[(size_t)(t0+tt)*3 + 2], e2*0.0625f);
    }
  }
}

// ---------------- LayerNorm (H=1024), optional bf16 residual, bf16 or f32 out ----------------
__global__ __launch_bounds__(256)
void k_ln(const u16* __restrict__ X, const u16* __restrict__ R,
          const float* __restrict__ gam, const float* __restrict__ bet,
          u16* __restrict__ outb, float* __restrict__ outf)
{
  __shared__ float rs[4], rq[4];
  const int t = blockIdx.x, tid = threadIdx.x;
  const size_t base = (size_t)t*1024 + tid*4;
  u16x4 xv = *(const u16x4*)&X[base];
  float v[4];
  #pragma unroll
  for (int i = 0; i < 4; ++i) v[i] = bf2f(xv[i]);
  if (R){
    u16x4 rv = *(const u16x4*)&R[base];
    #pragma unroll
    for (int i = 0; i < 4; ++i) v[i] += bf2f(rv[i]);
  }
  float s = v[0]+v[1]+v[2]+v[3];
  float q = v[0]*v[0]+v[1]*v[1]+v[2]*v[2]+v[3]*v[3];
  #pragma unroll
  for (int m = 1; m < 64; m <<= 1){ s += __shfl_xor(s, m); q += __shfl_xor(q, m); }
  if ((tid & 63) == 0){ rs[tid>>6] = s; rq[tid>>6] = q; }
  __syncthreads();
  s = rs[0]+rs[1]+rs[2]+rs[3];
  q = rq[0]+rq[1]+rq[2]+rq[3];
  float mean = s * (1.f/1024.f);
  float var  = q * (1.f/1024.f) - mean*mean;
  float rstd = rsqrtf(var + 1e-5f);
  int c0 = tid*4;
  if (outb){
    u16x4 o;
    #pragma unroll
    for (int i = 0; i < 4; ++i) o[i] = f2bf((v[i]-mean)*rstd*gam[c0+i] + bet[c0+i]);
    *(u16x4*)&outb[base] = o;
  } else {
    float4 o;
    o.x = (v[0]-mean)*rstd*gam[c0+0] + bet[c0+0];
    o.y = (v[1]-mean)*rstd*gam[c0+1] + bet[c0+1];
    o.z = (v[2]-mean)*rstd*gam[c0+2] + bet[c0+2];
    o.w = (v[3]-mean)*rstd*gam[c0+3] + bet[c0+3];
    *(float4*)&outf[base] = o;
  }
}

// ---------------- host launcher ----------------
extern "C" void kernel_launch(void* const* d_in, const int* in_sizes, int n_in,
                              void* d_out, int out_size, void* d_ws, size_t ws_size,
                              hipStream_t stream)
{
  (void)in_sizes; (void)n_in; (void)out_size;
  const float* x0  = (const float*)d_in[0];
  const float* x1  = (const float*)d_in[1];
  const float* x2  = (const float*)d_in[2];
  const float* sc  = (const float*)d_in[3];
  const float* Wp0 = (const float*)d_in[4];  const float* bp0 = (const float*)d_in[5];
  const float* Wp1 = (const float*)d_in[6];  const float* bp1 = (const float*)d_in[7];
  const float* Wq  = (const float*)d_in[8];  const float* bq  = (const float*)d_in[9];
  const float* Wk  = (const float*)d_in[10]; const float* bk  = (const float*)d_in[11];
  const float* Wv  = (const float*)d_in[12]; const float* bv  = (const float*)d_in[13];
  const float* Wo  = (const float*)d_in[14]; const float* bo  = (const float*)d_in[15];
  const float* qt  = (const float*)d_in[16];
  const float* g1  = (const float*)d_in[17]; const float* be1 = (const float*)d_in[18];
  const float* g2  = (const float*)d_in[19]; const float* be2 = (const float*)d_in[20];
  const float* W1  = (const float*)d_in[21]; const float* b1  = (const float*)d_in[22];
  const float* W2  = (const float*)d_in[23]; const float* b2  = (const float*)d_in[24];

  char* ws = (char*)d_ws;
  size_t off = 0;
  auto alloc = [&](size_t b)->char*{ char* p = ws + off; off += (b + 255) & ~(size_t)255; return p; };

  u16* Wp0b = (u16*)alloc((size_t)1024*256*2);
  u16* Wp1b = (u16*)alloc((size_t)1024*512*2);
  u16* Wqb  = (u16*)alloc((size_t)1024*1024*2);
  u16* Wkb  = (u16*)alloc((size_t)1024*1024*2);
  u16* Wvb  = (u16*)alloc((size_t)1024*1024*2);
  u16* Wob  = (u16*)alloc((size_t)1024*1024*2);
  u16* W1b  = (u16*)alloc((size_t)4096*1024*2);
  u16* W2b  = (u16*)alloc((size_t)1024*4096*2);
  char* stackedR = alloc((size_t)3*BT*1024*2);   // stacked [3T,1024]; later ff1 chunk
  char* regA = alloc((size_t)BT*1024*2);         // x0b+x1b -> Qb -> attn_out -> ff2
  char* regB = alloc((size_t)BT*1024*2);         // qb -> ctx -> fused1
  float* wacc = (float*)alloc((size_t)BT*3*4);
  if (off > ws_size) return;  // workspace too small; fail visibly

  u16* stackedb = (u16*)stackedR;
  u16* ff1c = (u16*)stackedR;
  u16* x0b = (u16*)regA;
  u16* x1b = (u16*)(regA + (size_t)BT*256*2);
  u16* Qb  = (u16*)regA;
  u16* aob = (u16*)regA;
  u16* ff2b = (u16*)regA;
  u16* qb  = (u16*)regB;
  u16* ctxb = (u16*)regB;
  u16* f1b = (u16*)regB;

  hipMemsetAsync(wacc, 0, (size_t)BT*3*4, stream);

  dim3 B256(256), B512(512);
  auto cast4 = [&](const float* s, u16* d, int n){
    k_cast4<<<dim3(1024), B256, 0, stream>>>(s, d, n >> 2);
  };
  cast4(Wp0, Wp0b, 1024*256); cast4(Wp1, Wp1b, 1024*512);
  cast4(Wq, Wqb, 1024*1024);  cast4(Wk, Wkb, 1024*1024);
  cast4(Wv, Wvb, 1024*1024);  cast4(Wo, Wob, 1024*1024);
  cast4(W1, W1b, 4096*1024);  cast4(W2, W2b, 4096*1024);
  cast4(x0, x0b, BT*256);     cast4(x1, x1b, BT*512);
  k_pack_x2<<<dim3(2048), B256, 0, stream>>>(x2, stackedb, BT*256);
  k_qb<<<dim3(2048), B256, 0, stream>>>(qt, sc, qb, BT*256);

  k_gemm256<<<dim3(BT/256, 4), B512, 0, stream>>>(x0b, 256, Wp0b, 256, 256, bp0, stackedb, 3072, 0,    0);
  k_gemm256<<<dim3(BT/256, 4), B512, 0, stream>>>(x1b, 512, Wp1b, 512, 512, bp1, stackedb, 3072, 1024, 0);
  k_gemm256<<<dim3(BT/256, 4), B512, 0, stream>>>(qb, 1024, Wqb, 1024, 1024, bq, Qb, 1024, 0, 0);
  k_attn<<<dim3(8, BT/32), B256, 0, stream>>>(stackedb, Wkb, Wvb, bk, bv, Qb, ctxb, wacc);
  k_gemm256<<<dim3(BT/256, 4), B512, 0, stream>>>(ctxb, 1024, Wob, 1024, 1024, bo, aob, 1024, 0, 0);
  k_ln<<<dim3(BT), B256, 0, stream>>>(aob, nullptr, g1, be1, f1b, nullptr);

  for (int c = 0; c < 4; ++c){
    const u16* fa = f1b + (size_t)c*8192*1024;
    k_gemm256<<<dim3(32, 16), B512, 0, stream>>>(fa, 1024, W1b, 1024, 1024, b1, ff1c, 4096, 0, 1);
    k_gemm256<<<dim3(32, 4),  B512, 0, stream>>>(ff1c, 4096, W2b, 4096, 4096, b2,
                                                 ff2b + (size_t)c*8192*1024, 1024, 0, 0);
  }
  float* outf = (float*)d_out;
  k_ln<<<dim3(BT), B256, 0, stream>>>(ff2b, f1b, g2, be2, nullptr, outf);
  k_copyf<<<dim3(384), B256, 0, stream>>>(wacc, outf + (size_t)BT*1024, BT*3);
}

// Round 4
// 2041.787 us; speedup vs baseline: 1.0161x; 1.0161x over previous
//
#include <hip/hip_runtime.h>
#include <hip/hip_bf16.h>
#include <math.h>

#define BT 32768        // B*T tokens
#define HH 1024

typedef unsigned short u16;
typedef __attribute__((ext_vector_type(4))) unsigned short u16x4;
typedef __attribute__((ext_vector_type(8))) __bf16 bf16x8;
typedef __attribute__((ext_vector_type(4))) float f32x4;

#define DEVI static __device__ __forceinline__

DEVI u16 f2bf(float f){
  unsigned u = __builtin_bit_cast(unsigned, f);
  u += 0x7FFFu + ((u >> 16) & 1u);
  return (u16)(u >> 16);
}
DEVI float bf2f(u16 h){
  unsigned u = ((unsigned)h) << 16;
  return __builtin_bit_cast(float, u);
}
DEVI void gl_lds16(const void* g, void* l){
  __builtin_amdgcn_global_load_lds((const __attribute__((address_space(1))) void*)g,
                                   (__attribute__((address_space(3))) void*)l, 16, 0, 0);
}
// T2 swizzle: 16B-granule XOR within a 64-elem (128B) row. elem units of u16. Involution.
DEVI int swz(int row, int elem){ return elem ^ ((row & 7) << 3); }

// ---------------- elementwise prep kernels ----------------
__global__ void k_cast4(const float* __restrict__ s, u16* __restrict__ d, int n4){
  int i = blockIdx.x*blockDim.x + threadIdx.x;
  int st = gridDim.x*blockDim.x;
  for (; i < n4; i += st){
    float4 v = ((const float4*)s)[i];
    u16x4 o = { f2bf(v.x), f2bf(v.y), f2bf(v.z), f2bf(v.w) };
    ((u16x4*)d)[i] = o;
  }
}

// x2 -> stacked slot 2 (ld 3072)
__global__ void k_pack_x2(const float* __restrict__ s, u16* __restrict__ d, int n4){
  int i = blockIdx.x*blockDim.x + threadIdx.x;
  int st = gridDim.x*blockDim.x;
  for (; i < n4; i += st){
    int e = i*4; int t = e >> 10; int c = e & 1023;
    float4 v = *(const float4*)&s[e];
    u16x4 o = { f2bf(v.x), f2bf(v.y), f2bf(v.z), f2bf(v.w) };
    *(u16x4*)&d[(size_t)t*3072 + 2048 + c] = o;
  }
}

// qb = bf16(query_token + static_context)
__global__ void k_qb(const float* __restrict__ qt, const float* __restrict__ sc,
                     u16* __restrict__ d, int n4){
  int i = blockIdx.x*blockDim.x + threadIdx.x;
  int st = gridDim.x*blockDim.x;
  for (; i < n4; i += st){
    int e = i*4; int c = e & 1023;
    float4 v = *(const float4*)&sc[e];
    float4 q = *(const float4*)&qt[c];
    u16x4 o = { f2bf(v.x+q.x), f2bf(v.y+q.y), f2bf(v.z+q.z), f2bf(v.w+q.w) };
    ((u16x4*)d)[i] = o;
  }
}

__global__ void k_copyf(const float* __restrict__ s, float* __restrict__ d, int n){
  int i = blockIdx.x*blockDim.x + threadIdx.x;
  int st = gridDim.x*blockDim.x;
  for (; i < n; i += st) d[i] = s[i];
}

// ---------------- 256x256 GEMM, BK=64, 8 waves, 8-phase counted-vmcnt schedule ----
// C[M,N](bf16) = A[M,K](bf16) @ B[N,K]^T + bias, opt gelu.
// 4 phases per K-tile (quadrants A0B0,A1B0,A0B1,A1B1 of the per-wave 128x64 output);
// staging: ph0:A1(t+1), ph1:B1(t+1), ph2:B0(t+2), ph3:A0(t+2) -- each stage targets a
// region whose last reader completed before a prior end-of-phase barrier (lgkmcnt(0)
// precedes each barrier). One vmcnt(6) per K-tile certifies tile t's 4 halves, with
// 3 half-tiles left in flight (template-matching).
__global__ __launch_bounds__(512, 2)
void k_gemm8p(const u16* __restrict__ A, int lda,
              const u16* __restrict__ B, int ldb, int K,
              const float* __restrict__ bias,
              u16* __restrict__ C, int ldc, int col0, int act)
{
  __shared__ u16 As[2][256*64];   // [buf][slot=mi*128+wr*64+q][64]
  __shared__ u16 Bs[2][256*64];   // [buf][slot=nj*128+wc*32+k ][64]
  const int tid = threadIdx.x, lane = tid & 63, wid = tid >> 6;
  const int wr = wid >> 2, wc = wid & 3;
  const int r15 = lane & 15, g = lane >> 4;
  const int m0 = blockIdx.x * 256, n0 = blockIdx.y * 256;
  const int nt = K >> 6;
  f32x4 acc[8][4] = {};
  const int srow = tid >> 3;            // 0..63
  const int scol = (tid & 7) * 8;       // 16B granule

  auto stA = [&](int buf, int half, int t){
    int tt = t < nt ? t : nt-1; int k0 = tt*64;   // clamp keeps vmcnt accounting uniform
    #pragma unroll
    for (int l = 0; l < 2; ++l){
      int slot = half*128 + l*64 + srow;
      int srcrow = m0 + l*128 + half*64 + srow;
      gl_lds16(A + (size_t)srcrow*lda + k0 + swz(slot, scol), &As[buf][slot*64 + scol]);
    }
  };
  auto stB = [&](int buf, int nj, int t){
    int tt = t < nt ? t : nt-1; int k0 = tt*64;
    #pragma unroll
    for (int l = 0; l < 2; ++l){
      int slot = nj*128 + l*64 + srow;
      int wck = l*64 + srow; int wq = wck >> 5, kq = wck & 31;
      int srcrow = n0 + wq*64 + nj*32 + kq;
      gl_lds16(B + (size_t)srcrow*ldb + k0 + swz(slot, scol), &Bs[buf][slot*64 + scol]);
    }
  };

#define MFMA_QUAD(BUF, MI, NJ) do{ \
    bf16x8 av[4][2], bv[2][2]; \
    _Pragma("unroll") for (int i = 0; i < 4; ++i){ int sa = MI*128 + wr*64 + i*16 + r15; \
      _Pragma("unroll") for (int k2 = 0; k2 < 2; ++k2) \
        av[i][k2] = *(const bf16x8*)&As[BUF][sa*64 + swz(sa, k2*32 + g*8)]; } \
    _Pragma("unroll") for (int jj = 0; jj < 2; ++jj){ int sb = NJ*128 + wc*32 + jj*16 + r15; \
      _Pragma("unroll") for (int k2 = 0; k2 < 2; ++k2) \
        bv[jj][k2] = *(const bf16x8*)&Bs[BUF][sb*64 + swz(sb, k2*32 + g*8)]; } \
    asm volatile("s_waitcnt lgkmcnt(0)" ::: "memory"); \
    __builtin_amdgcn_sched_barrier(0); \
    __builtin_amdgcn_s_setprio(1); \
    _Pragma("unroll") for (int k2 = 0; k2 < 2; ++k2) \
      _Pragma("unroll") for (int i = 0; i < 4; ++i) \
        _Pragma("unroll") for (int jj = 0; jj < 2; ++jj) \
          acc[MI*4+i][NJ*2+jj] = __builtin_amdgcn_mfma_f32_16x16x32_bf16( \
              av[i][k2], bv[jj][k2], acc[MI*4+i][NJ*2+jj], 0, 0, 0); \
    __builtin_amdgcn_s_setprio(0); \
    __builtin_amdgcn_s_barrier(); \
    __builtin_amdgcn_sched_barrier(0); \
  }while(0)

  // prologue: tile0 fully + B0,A0 of tile1  (FIFO order matters for vmcnt math)
  stA(0,0,0); stB(0,0,0); stA(0,1,0); stB(0,1,0); stB(1,0,1); stA(1,0,1);

  for (int t = 0; t < nt; ++t){
    const int cur = t & 1, opp = cur ^ 1;
    // ph0: stage A1(t+1)->opp; wait tile t landed; reads AFTER the certify barrier
    stA(opp, 1, t+1);
    asm volatile("s_waitcnt vmcnt(6)" ::: "memory");
    __builtin_amdgcn_s_barrier();
    __builtin_amdgcn_sched_barrier(0);
    MFMA_QUAD(cur, 0, 0);
    // ph1: reads certified since ph0; stage B1(t+1)->opp (opp B1 last read: prev tile ph3)
    stB(opp, 1, t+1);
    __builtin_amdgcn_s_barrier();
    __builtin_amdgcn_sched_barrier(0);
    MFMA_QUAD(cur, 1, 0);
    // ph2: stage B0(t+2)->cur (cur B0 last read ph1, end-barriered)
    stB(cur, 0, t+2);
    __builtin_amdgcn_s_barrier();
    __builtin_amdgcn_sched_barrier(0);
    MFMA_QUAD(cur, 0, 1);
    // ph3: stage A0(t+2)->cur (cur A0 last read ph2)
    stA(cur, 0, t+2);
    __builtin_amdgcn_s_barrier();
    __builtin_amdgcn_sched_barrier(0);
    MFMA_QUAD(cur, 1, 1);
  }
  asm volatile("s_waitcnt vmcnt(0)" ::: "memory");

  #pragma unroll
  for (int j = 0; j < 4; ++j){
    int col = wc*64 + j*16 + r15;
    float bb = bias ? bias[n0 + col] : 0.f;
    #pragma unroll
    for (int i = 0; i < 8; ++i){
      #pragma unroll
      for (int jj = 0; jj < 4; ++jj){
        int row = wr*128 + i*16 + g*4 + jj;
        float v = acc[i][j][jj] + bb;
        if (act == 1) v = 0.5f * v * (1.f + erff(v * 0.70710678118654752f));
        C[(size_t)(m0+row)*ldc + col0 + n0 + col] = f2bf(v);
      }
    }
  }
#undef MFMA_QUAD
}

// ---------------- fused K/V projection + M=3 cross-attention (R2 form) ----------------
__global__ __launch_bounds__(256, 3)
void k_attn(const u16* __restrict__ S, const u16* __restrict__ Wk, const u16* __restrict__ Wv,
            const float* __restrict__ bk, const float* __restrict__ bv,
            const u16* __restrict__ Q, u16* __restrict__ ctx, float* __restrict__ wacc)
{
  __shared__ __align__(16) char smem[45056];
  u16* As  = (u16*)smem;                    // 96x64
  u16* Bk  = (u16*)(smem + 12288);          // 128x64
  u16* Bv  = (u16*)(smem + 12288 + 16384);  // 128x64
  u16* Vl  = (u16*)smem;                    // epilogue: 96x128 bf16
  u16* Ql  = (u16*)(smem + 24576);          // epilogue: 32x128 bf16
  float* Sl = (float*)(smem + 24576 + 8192);// epilogue: 2 heads x 96 rows

  const int tid = threadIdx.x, lane = tid & 63, wid = tid >> 6;
  const int wr = wid >> 1, wcH = wid & 1;
  const int r15 = lane & 15, g = lane >> 4;
  const int bt = blockIdx.x, bn = blockIdx.y;
  const int row0 = bt * 96, n0 = bn * 128;

  f32x4 aK[3][4] = {}; f32x4 aV[3][4] = {};

  for (int k0 = 0; k0 < 1024; k0 += 64){
    #pragma unroll
    for (int it = 0; it < 3; ++it){
      int c = it*256 + tid; int row = c >> 3;
      int ke = swz(row, (c & 7) * 8);
      gl_lds16(S + (size_t)(row0+row)*1024 + k0 + ke, As + c*8);
    }
    #pragma unroll
    for (int it = 0; it < 4; ++it){
      int c = it*256 + tid; int row = c >> 3;
      int ke = swz(row, (c & 7) * 8);
      gl_lds16(Wk + (size_t)(n0+row)*1024 + k0 + ke, Bk + c*8);
      gl_lds16(Wv + (size_t)(n0+row)*1024 + k0 + ke, Bv + c*8);
    }
    __syncthreads();
    #pragma unroll
    for (int kk = 0; kk < 64; kk += 32){
      bf16x8 av[3], b1[4], b2[4];
      #pragma unroll
      for (int i = 0; i < 3; ++i){
        int row = wr*48 + i*16 + r15;
        av[i] = *(const bf16x8*)&As[row*64 + swz(row, kk + g*8)];
      }
      #pragma unroll
      for (int j = 0; j < 4; ++j){
        int row = wcH*64 + j*16 + r15;
        b1[j] = *(const bf16x8*)&Bk[row*64 + swz(row, kk + g*8)];
        b2[j] = *(const bf16x8*)&Bv[row*64 + swz(row, kk + g*8)];
      }
      #pragma unroll
      for (int i = 0; i < 3; ++i)
        #pragma unroll
        for (int j = 0; j < 4; ++j){
          aK[i][j] = __builtin_amdgcn_mfma_f32_16x16x32_bf16(av[i], b1[j], aK[i][j], 0, 0, 0);
          aV[i][j] = __builtin_amdgcn_mfma_f32_16x16x32_bf16(av[i], b2[j], aV[i][j], 0, 0, 0);
        }
    }
    __syncthreads();
  }

  // V (+bias) -> LDS as bf16
  #pragma unroll
  for (int j = 0; j < 4; ++j){
    int col = wcH*64 + j*16 + r15;
    float bvv = bv[n0 + col];
    #pragma unroll
    for (int i = 0; i < 3; ++i)
      #pragma unroll
      for (int jj = 0; jj < 4; ++jj){
        int row = wr*48 + i*16 + g*4 + jj;
        Vl[row*128 + col] = f2bf(aV[i][j][jj] + bvv);
      }
  }
  // stage Q tile [32 tokens][128 cols]
  #pragma unroll
  for (int it = 0; it < 4; ++it){
    int c4 = it*256 + tid;
    int tt = c4 >> 5, cc = (c4 & 31)*4;
    *(u16x4*)&Ql[tt*128 + cc] = *(const u16x4*)&Q[(size_t)(bt*32 + tt)*1024 + n0 + cc];
  }
  __syncthreads();

  // scores
  float bkv[4];
  #pragma unroll
  for (int j = 0; j < 4; ++j) bkv[j] = bk[n0 + wcH*64 + j*16 + r15];
  #pragma unroll
  for (int i = 0; i < 3; ++i){
    #pragma unroll
    for (int jj = 0; jj < 4; ++jj){
      int row = wr*48 + i*16 + g*4 + jj;
      int tt = row / 3;
      float s = 0.f;
      #pragma unroll
      for (int j = 0; j < 4; ++j){
        float qv = bf2f(Ql[tt*128 + wcH*64 + j*16 + r15]);
        s += (aK[i][j][jj] + bkv[j]) * qv;
      }
      s += __shfl_xor(s, 1); s += __shfl_xor(s, 2);
      s += __shfl_xor(s, 4); s += __shfl_xor(s, 8);
      if (r15 == 0) Sl[wcH*96 + row] = s * 0.125f;
    }
  }
  __syncthreads();

  // softmax over m=3, ctx, head-averaged weights
  const int t0 = bt*32;
  #pragma unroll
  for (int it = 0; it < 16; ++it){
    int idx = it*256 + tid;
    int tt = idx >> 7, col = idx & 127;
    int h = col >> 6;
    float s0 = Sl[h*96 + tt*3 + 0];
    float s1 = Sl[h*96 + tt*3 + 1];
    float s2 = Sl[h*96 + tt*3 + 2];
    float mx = fmaxf(s0, fmaxf(s1, s2));
    float e0 = expf(s0-mx), e1 = expf(s1-mx), e2 = expf(s2-mx);
    float inv = 1.f/(e0+e1+e2);
    e0 *= inv; e1 *= inv; e2 *= inv;
    float c = e0*bf2f(Vl[(tt*3+0)*128 + col])
            + e1*bf2f(Vl[(tt*3+1)*128 + col])
            + e2*bf2f(Vl[(tt*3+2)*128 + col]);
    ctx[(size_t)(t0+tt)*1024 + n0 + col] = f2bf(c);
    if ((col & 63) == 0){
      atomicAdd(&wacc[(size_t)(t0+tt)*3 + 0], e0*0.0625f);
      atomicAdd(&wacc[(size_t)(t0+tt)*3 + 1], e1*0.0625f);
      atomicAdd(&wacc[(size_t)(t0+tt)*3 + 2], e2*0.0625f);
    }
  }
}

// ---------------- LayerNorm (H=1024), optional bf16 residual, bf16 or f32 out ----------------
__global__ __launch_bounds__(256)
void k_ln(const u16* __restrict__ X, const u16* __restrict__ R,
          const float* __restrict__ gam, const float* __restrict__ bet,
          u16* __restrict__ outb, float* __restrict__ outf)
{
  __shared__ float rs[4], rq[4];
  const int t = blockIdx.x, tid = threadIdx.x;
  const size_t base = (size_t)t*1024 + tid*4;
  u16x4 xv = *(const u16x4*)&X[base];
  float v[4];
  #pragma unroll
  for (int i = 0; i < 4; ++i) v[i] = bf2f(xv[i]);
  if (R){
    u16x4 rv = *(const u16x4*)&R[base];
    #pragma unroll
    for (int i = 0; i < 4; ++i) v[i] += bf2f(rv[i]);
  }
  float s = v[0]+v[1]+v[2]+v[3];
  float q = v[0]*v[0]+v[1]*v[1]+v[2]*v[2]+v[3]*v[3];
  #pragma unroll
  for (int m = 1; m < 64; m <<= 1){ s += __shfl_xor(s, m); q += __shfl_xor(q, m); }
  if ((tid & 63) == 0){ rs[tid>>6] = s; rq[tid>>6] = q; }
  __syncthreads();
  s = rs[0]+rs[1]+rs[2]+rs[3];
  q = rq[0]+rq[1]+rq[2]+rq[3];
  float mean = s * (1.f/1024.f);
  float var  = q * (1.f/1024.f) - mean*mean;
  float rstd = rsqrtf(var + 1e-5f);
  int c0 = tid*4;
  if (outb){
    u16x4 o;
    #pragma unroll
    for (int i = 0; i < 4; ++i) o[i] = f2bf((v[i]-mean)*rstd*gam[c0+i] + bet[c0+i]);
    *(u16x4*)&outb[base] = o;
  } else {
    float4 o;
    o.x = (v[0]-mean)*rstd*gam[c0+0] + bet[c0+0];
    o.y = (v[1]-mean)*rstd*gam[c0+1] + bet[c0+1];
    o.z = (v[2]-mean)*rstd*gam[c0+2] + bet[c0+2];
    o.w = (v[3]-mean)*rstd*gam[c0+3] + bet[c0+3];
    *(float4*)&outf[base] = o;
  }
}

// ---------------- host launcher ----------------
extern "C" void kernel_launch(void* const* d_in, const int* in_sizes, int n_in,
                              void* d_out, int out_size, void* d_ws, size_t ws_size,
                              hipStream_t stream)
{
  (void)in_sizes; (void)n_in; (void)out_size;
  const float* x0  = (const float*)d_in[0];
  const float* x1  = (const float*)d_in[1];
  const float* x2  = (const float*)d_in[2];
  const float* sc  = (const float*)d_in[3];
  const float* Wp0 = (const float*)d_in[4];  const float* bp0 = (const float*)d_in[5];
  const float* Wp1 = (const float*)d_in[6];  const float* bp1 = (const float*)d_in[7];
  const float* Wq  = (const float*)d_in[8];  const float* bq  = (const float*)d_in[9];
  const float* Wk  = (const float*)d_in[10]; const float* bk  = (const float*)d_in[11];
  const float* Wv  = (const float*)d_in[12]; const float* bv  = (const float*)d_in[13];
  const float* Wo  = (const float*)d_in[14]; const float* bo  = (const float*)d_in[15];
  const float* qt  = (const float*)d_in[16];
  const float* g1  = (const float*)d_in[17]; const float* be1 = (const float*)d_in[18];
  const float* g2  = (const float*)d_in[19]; const float* be2 = (const float*)d_in[20];
  const float* W1  = (const float*)d_in[21]; const float* b1  = (const float*)d_in[22];
  const float* W2  = (const float*)d_in[23]; const float* b2  = (const float*)d_in[24];

  char* ws = (char*)d_ws;
  size_t off = 0;
  auto alloc = [&](size_t b)->char*{ char* p = ws + off; off += (b + 255) & ~(size_t)255; return p; };

  u16* Wp0b = (u16*)alloc((size_t)1024*256*2);
  u16* Wp1b = (u16*)alloc((size_t)1024*512*2);
  u16* Wqb  = (u16*)alloc((size_t)1024*1024*2);
  u16* Wkb  = (u16*)alloc((size_t)1024*1024*2);
  u16* Wvb  = (u16*)alloc((size_t)1024*1024*2);
  u16* Wob  = (u16*)alloc((size_t)1024*1024*2);
  u16* W1b  = (u16*)alloc((size_t)4096*1024*2);
  u16* W2b  = (u16*)alloc((size_t)1024*4096*2);
  char* stackedR = alloc((size_t)3*BT*1024*2);   // stacked [3T,1024]; later ff1 chunk
  char* regA = alloc((size_t)BT*1024*2);         // x0b+x1b -> Qb -> attn_out -> ff2
  char* regB = alloc((size_t)BT*1024*2);         // qb -> ctx -> fused1
  float* wacc = (float*)alloc((size_t)BT*3*4);
  if (off > ws_size) return;  // workspace too small; fail visibly

  u16* stackedb = (u16*)stackedR;
  u16* ff1c = (u16*)stackedR;
  u16* x0b = (u16*)regA;
  u16* x1b = (u16*)(regA + (size_t)BT*256*2);
  u16* Qb  = (u16*)regA;
  u16* aob = (u16*)regA;
  u16* ff2b = (u16*)regA;
  u16* qb  = (u16*)regB;
  u16* ctxb = (u16*)regB;
  u16* f1b = (u16*)regB;

  hipMemsetAsync(wacc, 0, (size_t)BT*3*4, stream);

  dim3 B256(256), B512(512);
  auto cast4 = [&](const float* s, u16* d, int n){
    k_cast4<<<dim3(1024), B256, 0, stream>>>(s, d, n >> 2);
  };
  cast4(Wp0, Wp0b, 1024*256); cast4(Wp1, Wp1b, 1024*512);
  cast4(Wq, Wqb, 1024*1024);  cast4(Wk, Wkb, 1024*1024);
  cast4(Wv, Wvb, 1024*1024);  cast4(Wo, Wob, 1024*1024);
  cast4(W1, W1b, 4096*1024);  cast4(W2, W2b, 4096*1024);
  cast4(x0, x0b, BT*256);     cast4(x1, x1b, BT*512);
  k_pack_x2<<<dim3(2048), B256, 0, stream>>>(x2, stackedb, BT*256);
  k_qb<<<dim3(2048), B256, 0, stream>>>(qt, sc, qb, BT*256);

  k_gemm8p<<<dim3(BT/256, 4), B512, 0, stream>>>(x0b, 256, Wp0b, 256, 256, bp0, stackedb, 3072, 0,    0);
  k_gemm8p<<<dim3(BT/256, 4), B512, 0, stream>>>(x1b, 512, Wp1b, 512, 512, bp1, stackedb, 3072, 1024, 0);
  k_gemm8p<<<dim3(BT/256, 4), B512, 0, stream>>>(qb, 1024, Wqb, 1024, 1024, bq, Qb, 1024, 0, 0);
  k_attn<<<dim3(BT/32, 8), B256, 0, stream>>>(stackedb, Wkb, Wvb, bk, bv, Qb, ctxb, wacc);
  k_gemm8p<<<dim3(BT/256, 4), B512, 0, stream>>>(ctxb, 1024, Wob, 1024, 1024, bo, aob, 1024, 0, 0);
  k_ln<<<dim3(BT), B256, 0, stream>>>(aob, nullptr, g1, be1, f1b, nullptr);

  for (int c = 0; c < 2; ++c){          // 2 chunks of 16384 rows (ff1c fits stacked buffer)
    const u16* fa = f1b + (size_t)c*16384*1024;
    k_gemm8p<<<dim3(64, 16), B512, 0, stream>>>(fa, 1024, W1b, 1024, 1024, b1, ff1c, 4096, 0, 1);
    k_gemm8p<<<dim3(64, 4),  B512, 0, stream>>>(ff1c, 4096, W2b, 4096, 4096, b2,
                                                ff2b + (size_t)c*16384*1024, 1024, 0, 0);
  }
  float* outf = (float*)d_out;
  k_ln<<<dim3(BT), B256, 0, stream>>>(ff2b, f1b, g2, be2, nullptr, outf);
  k_copyf<<<dim3(384), B256, 0, stream>>>(wacc, outf + (size_t)BT*1024, BT*3);
}

// Round 5
// 1591.458 us; speedup vs baseline: 1.3036x; 1.2830x over previous
//
#include <hip/hip_runtime.h>
#include <hip/hip_bf16.h>
#include <math.h>

#define BT 32768        // B*T tokens
#define HH 1024

typedef unsigned short u16;
typedef __attribute__((ext_vector_type(4))) unsigned short u16x4;
typedef __attribute__((ext_vector_type(8))) __bf16 bf16x8;
typedef __attribute__((ext_vector_type(4))) float f32x4;

#define DEVI static __device__ __forceinline__

DEVI u16 f2bf(float f){
  unsigned u = __builtin_bit_cast(unsigned, f);
  u += 0x7FFFu + ((u >> 16) & 1u);
  return (u16)(u >> 16);
}
DEVI float bf2f(u16 h){
  unsigned u = ((unsigned)h) << 16;
  return __builtin_bit_cast(float, u);
}
DEVI void gl_lds16(const void* g, void* l){
  __builtin_amdgcn_global_load_lds((const __attribute__((address_space(1))) void*)g,
                                   (__attribute__((address_space(3))) void*)l, 16, 0, 0);
}
// T2 swizzle: 16B-granule XOR within a 64-elem (128B) row. elem units of u16. Involution.
DEVI int swz(int row, int elem){ return elem ^ ((row & 7) << 3); }

// ---------------- elementwise prep kernels ----------------
__global__ void k_cast4(const float* __restrict__ s, u16* __restrict__ d, int n4){
  int i = blockIdx.x*blockDim.x + threadIdx.x;
  int st = gridDim.x*blockDim.x;
  for (; i < n4; i += st){
    float4 v = ((const float4*)s)[i];
    u16x4 o = { f2bf(v.x), f2bf(v.y), f2bf(v.z), f2bf(v.w) };
    ((u16x4*)d)[i] = o;
  }
}

// qb = bf16(query_token + static_context)
__global__ void k_qb(const float* __restrict__ qt, const float* __restrict__ sc,
                     u16* __restrict__ d, int n4){
  int i = blockIdx.x*blockDim.x + threadIdx.x;
  int st = gridDim.x*blockDim.x;
  for (; i < n4; i += st){
    int e = i*4; int c = e & 1023;
    float4 v = *(const float4*)&sc[e];
    float4 q = *(const float4*)&qt[c];
    u16x4 o = { f2bf(v.x+q.x), f2bf(v.y+q.y), f2bf(v.z+q.z), f2bf(v.w+q.w) };
    ((u16x4*)d)[i] = o;
  }
}

__global__ void k_copyf(const float* __restrict__ s, float* __restrict__ d, int n){
  int i = blockIdx.x*blockDim.x + threadIdx.x;
  int st = gridDim.x*blockDim.x;
  for (; i < n; i += st) d[i] = s[i];
}

// transpose-cast: s[R][C] f32 -> d[C][R] bf16
__global__ void k_transcast(const float* __restrict__ s, u16* __restrict__ d, int R, int C){
  __shared__ float tile[32][33];
  int c0 = blockIdx.x*32, r0 = blockIdx.y*32;
  int tx = threadIdx.x & 31, ty = threadIdx.x >> 5;   // 32 x 8
  #pragma unroll
  for (int i = 0; i < 32; i += 8) tile[ty+i][tx] = s[(size_t)(r0+ty+i)*C + c0+tx];
  __syncthreads();
  #pragma unroll
  for (int i = 0; i < 32; i += 8) d[(size_t)(c0+ty+i)*R + r0+tx] = f2bf(tile[tx][ty+i]);
}

// out[row] = dot(W[row,:](bf16), x(f32)) + badd[row], rows = gridDim.x*4
__global__ void k_matvec(const u16* __restrict__ W, const float* __restrict__ x,
                         const float* __restrict__ badd, float* __restrict__ out, int K){
  int row = blockIdx.x*4 + (threadIdx.x>>6);
  int lane = threadIdx.x & 63;
  float s = 0.f;
  for (int k = lane; k < K; k += 64) s += bf2f(W[(size_t)row*K + k]) * x[k];
  #pragma unroll
  for (int m = 1; m < 64; m <<= 1) s += __shfl_xor(s, m);
  if (lane == 0) out[row] = s + badd[row];
}

// ---------------- GEMM: C[M,N](bf16) = A[M,K](bf16) @ B[N,K]^T + bias, opt gelu (R2-proven) ---
__global__ __launch_bounds__(256, 3)
void k_gemm(const u16* __restrict__ A, int lda,
            const u16* __restrict__ B, int ldb, int K,
            const float* __restrict__ bias,
            u16* __restrict__ C, int ldc, int col0, int act)
{
  __shared__ u16 As[128*64];
  __shared__ u16 Bs[128*64];
  const int tid = threadIdx.x, lane = tid & 63, wid = tid >> 6;
  const int wr = wid >> 1, wc = wid & 1;
  const int r15 = lane & 15, g = lane >> 4;
  const int m0 = blockIdx.x * 128, n0 = blockIdx.y * 128;
  f32x4 acc[4][4] = {};

  for (int k0 = 0; k0 < K; k0 += 64){
    #pragma unroll
    for (int it = 0; it < 4; ++it){
      int c = it*256 + tid;
      int row = c >> 3;
      int ke = swz(row, (c & 7) * 8);
      gl_lds16(A + (size_t)(m0+row)*lda + (k0+ke), As + c*8);
      gl_lds16(B + (size_t)(n0+row)*ldb + (k0+ke), Bs + c*8);
    }
    __syncthreads();
    #pragma unroll
    for (int kk = 0; kk < 64; kk += 32){
      bf16x8 av[4], bvv[4];
      #pragma unroll
      for (int i = 0; i < 4; ++i){
        int row = wr*64 + i*16 + r15;
        av[i] = *(const bf16x8*)&As[row*64 + swz(row, kk + g*8)];
      }
      #pragma unroll
      for (int j = 0; j < 4; ++j){
        int row = wc*64 + j*16 + r15;
        bvv[j] = *(const bf16x8*)&Bs[row*64 + swz(row, kk + g*8)];
      }
      #pragma unroll
      for (int i = 0; i < 4; ++i)
        #pragma unroll
        for (int j = 0; j < 4; ++j)
          acc[i][j] = __builtin_amdgcn_mfma_f32_16x16x32_bf16(av[i], bvv[j], acc[i][j], 0, 0, 0);
    }
    __syncthreads();
  }
  #pragma unroll
  for (int j = 0; j < 4; ++j){
    int col = wc*64 + j*16 + r15;
    float bb = bias ? bias[n0 + col] : 0.f;
    #pragma unroll
    for (int i = 0; i < 4; ++i){
      #pragma unroll
      for (int jj = 0; jj < 4; ++jj){
        int row = wr*64 + i*16 + g*4 + jj;
        float v = acc[i][j][jj] + bb;
        if (act == 1) v = 0.5f * v * (1.f + erff(v * 0.70710678118654752f));
        C[(size_t)(m0+row)*ldc + col0 + n0 + col] = f2bf(v);
      }
    }
  }
}

// ---------------- two-pass fused attention with composite per-modality K/V weights ------
// Block: 128 tokens x 128 cols (2 heads), 512 threads = 8 waves (wr 0..3 token-quarter, h 0..1).
// Pass 1: per modality m, K-GEMM (x_m @ Wc_m[0:1024]^T) -> scores via per-lane dot with Q,
//         shfl-reduce over 16 head-dim lanes -> Sl. Then softmax(3) in place + weights atomics.
// Pass 2: per modality m, V-GEMM (rows 1024+ of Wc_m) -> ctx += p_m * (V_m + bv_m); store bf16.
// bn = blockIdx&7 -> each XCD's blocks share one 128-col weight panel (L2-resident).
__global__ __launch_bounds__(512, 4)
void k_attn2p(const u16* __restrict__ x0b, const u16* __restrict__ x1b, const u16* __restrict__ x2b,
              const u16* __restrict__ Wc0, const u16* __restrict__ Wc1, const u16* __restrict__ Wc2,
              const float* __restrict__ bc0, const float* __restrict__ bc1, const float* __restrict__ bc2,
              const u16* __restrict__ Qg, u16* __restrict__ ctx, float* __restrict__ wacc)
{
  __shared__ __align__(16) u16 As[128*64];   // 16KB token tile
  __shared__ __align__(16) u16 Bs[128*64];   // 16KB weight tile (K-half or V-half)
  __shared__ float Sl[2*128*3];              // scores -> probs (in place)

  const int tid = threadIdx.x, lane = tid & 63, wid = tid >> 6;
  const int wr = wid >> 1, h = wid & 1;
  const int r15 = lane & 15, g = lane >> 4;
  const int bid = blockIdx.x;
  const int bn = bid & 7, btb = bid >> 3;
  const int t0 = btb * 128, n0 = bn * 128;

  const u16* Xs[3] = { x0b, x1b, x2b };
  const u16* Ws[3] = { Wc0, Wc1, Wc2 };
  const float* Bc[3] = { bc0, bc1, bc2 };
  const int Ks[3] = { 256, 512, 1024 };

  const int srow = tid >> 3;            // 0..63
  const int scol = (tid & 7) * 8;       // 16B granule

  // ---------------- pass 1: scores ----------------
  #pragma unroll
  for (int m = 0; m < 3; ++m){
    const int K = Ks[m];
    const u16* X = Xs[m];
    const u16* W = Ws[m];
    f32x4 aK[2][4] = {};
    for (int k0 = 0; k0 < K; k0 += 64){
      #pragma unroll
      for (int l = 0; l < 2; ++l){
        int row = l*64 + srow;
        int ke = swz(row, scol);
        gl_lds16(X + (size_t)(t0+row)*K + k0 + ke, &As[row*64 + scol]);
        gl_lds16(W + (size_t)(n0+row)*K + k0 + ke, &Bs[row*64 + scol]);
      }
      __syncthreads();
      #pragma unroll
      for (int kk = 0; kk < 64; kk += 32){
        bf16x8 av[2], bv[4];
        #pragma unroll
        for (int i = 0; i < 2; ++i){
          int ra = wr*32 + i*16 + r15;
          av[i] = *(const bf16x8*)&As[ra*64 + swz(ra, kk + g*8)];
        }
        #pragma unroll
        for (int j = 0; j < 4; ++j){
          int rb = h*64 + j*16 + r15;
          bv[j] = *(const bf16x8*)&Bs[rb*64 + swz(rb, kk + g*8)];
        }
        #pragma unroll
        for (int i = 0; i < 2; ++i)
          #pragma unroll
          for (int j = 0; j < 4; ++j)
            aK[i][j] = __builtin_amdgcn_mfma_f32_16x16x32_bf16(av[i], bv[j], aK[i][j], 0, 0, 0);
      }
      __syncthreads();
    }
    // score: s(t) = sum_col Q[t,col]*(K[t,col]) / 8, col over this head's 64 dims
    float bkc[4];
    #pragma unroll
    for (int j = 0; j < 4; ++j) bkc[j] = Bc[m][n0 + h*64 + j*16 + r15];
    #pragma unroll
    for (int i = 0; i < 2; ++i){
      #pragma unroll
      for (int jj = 0; jj < 4; ++jj){
        int tt = wr*32 + i*16 + g*4 + jj;
        const u16* qrow = Qg + (size_t)(t0+tt)*1024 + n0 + h*64 + r15;
        float s = 0.f;
        #pragma unroll
        for (int j = 0; j < 4; ++j)
          s += (aK[i][j][jj] + bkc[j]) * bf2f(qrow[j*16]);
        s += __shfl_xor(s, 1); s += __shfl_xor(s, 2);
        s += __shfl_xor(s, 4); s += __shfl_xor(s, 8);
        if (r15 == 0) Sl[(h*128 + tt)*3 + m] = s * 0.125f;
      }
    }
  }
  __syncthreads();
  // softmax over m=3 (in place) + head-averaged weights
  if (tid < 256){
    int h2 = tid >> 7, tt = tid & 127;
    int base = (h2*128 + tt)*3;
    float s0 = Sl[base+0], s1 = Sl[base+1], s2 = Sl[base+2];
    float mx = fmaxf(s0, fmaxf(s1, s2));
    float e0 = expf(s0-mx), e1 = expf(s1-mx), e2 = expf(s2-mx);
    float inv = 1.f/(e0+e1+e2);
    e0 *= inv; e1 *= inv; e2 *= inv;
    Sl[base+0] = e0; Sl[base+1] = e1; Sl[base+2] = e2;
    atomicAdd(&wacc[(size_t)(t0+tt)*3 + 0], e0*0.0625f);
    atomicAdd(&wacc[(size_t)(t0+tt)*3 + 1], e1*0.0625f);
    atomicAdd(&wacc[(size_t)(t0+tt)*3 + 2], e2*0.0625f);
  }
  __syncthreads();

  // ---------------- pass 2: V + ctx ----------------
  f32x4 ctxa[2][4] = {};
  #pragma unroll
  for (int m = 0; m < 3; ++m){
    const int K = Ks[m];
    const u16* X = Xs[m];
    const u16* W = Ws[m] + (size_t)1024*K;   // V rows
    f32x4 aV[2][4] = {};
    for (int k0 = 0; k0 < K; k0 += 64){
      #pragma unroll
      for (int l = 0; l < 2; ++l){
        int row = l*64 + srow;
        int ke = swz(row, scol);
        gl_lds16(X + (size_t)(t0+row)*K + k0 + ke, &As[row*64 + scol]);
        gl_lds16(W + (size_t)(n0+row)*K + k0 + ke, &Bs[row*64 + scol]);
      }
      __syncthreads();
      #pragma unroll
      for (int kk = 0; kk < 64; kk += 32){
        bf16x8 av[2], bv[4];
        #pragma unroll
        for (int i = 0; i < 2; ++i){
          int ra = wr*32 + i*16 + r15;
          av[i] = *(const bf16x8*)&As[ra*64 + swz(ra, kk + g*8)];
        }
        #pragma unroll
        for (int j = 0; j < 4; ++j){
          int rb = h*64 + j*16 + r15;
          bv[j] = *(const bf16x8*)&Bs[rb*64 + swz(rb, kk + g*8)];
        }
        #pragma unroll
        for (int i = 0; i < 2; ++i)
          #pragma unroll
          for (int j = 0; j < 4; ++j)
            aV[i][j] = __builtin_amdgcn_mfma_f32_16x16x32_bf16(av[i], bv[j], aV[i][j], 0, 0, 0);
      }
      __syncthreads();
    }
    // fold: ctx += p_m * (V_m + bv_m)
    #pragma unroll
    for (int j = 0; j < 4; ++j){
      float bvv = Bc[m][1024 + n0 + h*64 + j*16 + r15];
      #pragma unroll
      for (int i = 0; i < 2; ++i){
        #pragma unroll
        for (int jj = 0; jj < 4; ++jj){
          int tt = wr*32 + i*16 + g*4 + jj;
          float p = Sl[(h*128 + tt)*3 + m];
          ctxa[i][j][jj] += p * (aV[i][j][jj] + bvv);
        }
      }
    }
  }
  // store ctx (bf16)
  #pragma unroll
  for (int i = 0; i < 2; ++i){
    #pragma unroll
    for (int jj = 0; jj < 4; ++jj){
      int tt = wr*32 + i*16 + g*4 + jj;
      #pragma unroll
      for (int j = 0; j < 4; ++j)
        ctx[(size_t)(t0+tt)*1024 + n0 + h*64 + j*16 + r15] = f2bf(ctxa[i][j][jj]);
    }
  }
}

// ---------------- LayerNorm (H=1024), optional bf16 residual, bf16 or f32 out ----------------
__global__ __launch_bounds__(256)
void k_ln(const u16* __restrict__ X, const u16* __restrict__ R,
          const float* __restrict__ gam, const float* __restrict__ bet,
          u16* __restrict__ outb, float* __restrict__ outf)
{
  __shared__ float rs[4], rq[4];
  const int t = blockIdx.x, tid = threadIdx.x;
  const size_t base = (size_t)t*1024 + tid*4;
  u16x4 xv = *(const u16x4*)&X[base];
  float v[4];
  #pragma unroll
  for (int i = 0; i < 4; ++i) v[i] = bf2f(xv[i]);
  if (R){
    u16x4 rv = *(const u16x4*)&R[base];
    #pragma unroll
    for (int i = 0; i < 4; ++i) v[i] += bf2f(rv[i]);
  }
  float s = v[0]+v[1]+v[2]+v[3];
  float q = v[0]*v[0]+v[1]*v[1]+v[2]*v[2]+v[3]*v[3];
  #pragma unroll
  for (int m = 1; m < 64; m <<= 1){ s += __shfl_xor(s, m); q += __shfl_xor(q, m); }
  if ((tid & 63) == 0){ rs[tid>>6] = s; rq[tid>>6] = q; }
  __syncthreads();
  s = rs[0]+rs[1]+rs[2]+rs[3];
  q = rq[0]+rq[1]+rq[2]+rq[3];
  float mean = s * (1.f/1024.f);
  float var  = q * (1.f/1024.f) - mean*mean;
  float rstd = rsqrtf(var + 1e-5f);
  int c0 = tid*4;
  if (outb){
    u16x4 o;
    #pragma unroll
    for (int i = 0; i < 4; ++i) o[i] = f2bf((v[i]-mean)*rstd*gam[c0+i] + bet[c0+i]);
    *(u16x4*)&outb[base] = o;
  } else {
    float4 o;
    o.x = (v[0]-mean)*rstd*gam[c0+0] + bet[c0+0];
    o.y = (v[1]-mean)*rstd*gam[c0+1] + bet[c0+1];
    o.z = (v[2]-mean)*rstd*gam[c0+2] + bet[c0+2];
    o.w = (v[3]-mean)*rstd*gam[c0+3] + bet[c0+3];
    *(float4*)&outf[base] = o;
  }
}

// ---------------- host launcher ----------------
extern "C" void kernel_launch(void* const* d_in, const int* in_sizes, int n_in,
                              void* d_out, int out_size, void* d_ws, size_t ws_size,
                              hipStream_t stream)
{
  (void)in_sizes; (void)n_in; (void)out_size;
  const float* x0  = (const float*)d_in[0];
  const float* x1  = (const float*)d_in[1];
  const float* x2  = (const float*)d_in[2];
  const float* sc  = (const float*)d_in[3];
  const float* Wp0 = (const float*)d_in[4];  const float* bp0 = (const float*)d_in[5];
  const float* Wp1 = (const float*)d_in[6];  const float* bp1 = (const float*)d_in[7];
  const float* Wq  = (const float*)d_in[8];  const float* bq  = (const float*)d_in[9];
  const float* Wk  = (const float*)d_in[10]; const float* bk  = (const float*)d_in[11];
  const float* Wv  = (const float*)d_in[12]; const float* bv  = (const float*)d_in[13];
  const float* Wo  = (const float*)d_in[14]; const float* bo  = (const float*)d_in[15];
  const float* qt  = (const float*)d_in[16];
  const float* g1  = (const float*)d_in[17]; const float* be1 = (const float*)d_in[18];
  const float* g2  = (const float*)d_in[19]; const float* be2 = (const float*)d_in[20];
  const float* W1  = (const float*)d_in[21]; const float* b1  = (const float*)d_in[22];
  const float* W2  = (const float*)d_in[23]; const float* b2  = (const float*)d_in[24];

  char* ws = (char*)d_ws;
  size_t off = 0;
  auto alloc = [&](size_t b)->char*{ char* p = ws + off; off += (b + 255) & ~(size_t)255; return p; };

  u16* Wqb   = (u16*)alloc((size_t)1024*1024*2);
  u16* Wob   = (u16*)alloc((size_t)1024*1024*2);
  u16* W1b   = (u16*)alloc((size_t)4096*1024*2);
  u16* W2b   = (u16*)alloc((size_t)1024*4096*2);
  u16* Wkvb  = (u16*)alloc((size_t)2048*1024*2);  // [Wk; Wv]
  u16* Wp0t  = (u16*)alloc((size_t)256*1024*2);   // Wp0^T
  u16* Wp1t  = (u16*)alloc((size_t)512*1024*2);   // Wp1^T
  u16* Wkv0c = (u16*)alloc((size_t)2048*256*2);   // [Wk;Wv]@Wp0
  u16* Wkv1c = (u16*)alloc((size_t)2048*512*2);   // [Wk;Wv]@Wp1
  float* bc0 = (float*)alloc((size_t)2048*4);
  float* bc1 = (float*)alloc((size_t)2048*4);
  float* bc2 = (float*)alloc((size_t)2048*4);
  char* regX  = alloc((size_t)BT*(256+512+1024)*2);  // x0b|x1b|x2b -> aob -> ff2b
  char* regQ1 = alloc((size_t)BT*1024*2);            // qb -> ctxb -> f1b
  char* regQ2 = alloc((size_t)BT*1024*2);            // Qb -> ff1c
  float* wacc = (float*)alloc((size_t)BT*3*4);
  if (off > ws_size) return;

  u16* x0b = (u16*)regX;
  u16* x1b = (u16*)(regX + (size_t)BT*256*2);
  u16* x2b = (u16*)(regX + (size_t)BT*768*2);
  u16* aob  = (u16*)regX;
  u16* ff2b = (u16*)regX;
  u16* qb   = (u16*)regQ1;
  u16* ctxb = (u16*)regQ1;
  u16* f1b  = (u16*)regQ1;
  u16* Qb   = (u16*)regQ2;
  u16* ff1c = (u16*)regQ2;

  hipMemsetAsync(wacc, 0, (size_t)BT*3*4, stream);

  dim3 B256(256), B512(512);
  auto cast4 = [&](const float* s, u16* d, int n, int grid){
    k_cast4<<<dim3(grid), B256, 0, stream>>>(s, d, n >> 2);
  };
  cast4(Wq, Wqb, 1024*1024, 1024);
  cast4(Wk, Wkvb, 1024*1024, 1024);
  cast4(Wv, Wkvb + (size_t)1024*1024, 1024*1024, 1024);
  cast4(Wo, Wob, 1024*1024, 1024);
  cast4(W1, W1b, 4096*1024, 1024);
  cast4(W2, W2b, 4096*1024, 1024);
  cast4(x0, x0b, BT*256, 1024);
  cast4(x1, x1b, BT*512, 1024);
  cast4(x2, x2b, BT*1024, 2048);
  k_transcast<<<dim3(8, 32),  B256, 0, stream>>>(Wp0, Wp0t, 1024, 256);
  k_transcast<<<dim3(16, 32), B256, 0, stream>>>(Wp1, Wp1t, 1024, 512);
  k_copyf<<<dim3(4), B256, 0, stream>>>(bk, bc2, 1024);
  k_copyf<<<dim3(4), B256, 0, stream>>>(bv, bc2 + 1024, 1024);
  k_matvec<<<dim3(512), B256, 0, stream>>>(Wkvb, bp0, bc2, bc0, 1024);
  k_matvec<<<dim3(512), B256, 0, stream>>>(Wkvb, bp1, bc2, bc1, 1024);
  k_qb<<<dim3(2048), B256, 0, stream>>>(qt, sc, qb, BT*256);

  // composite weights: Wkv @ Wp_m  (C[2048, IN_m])
  k_gemm<<<dim3(16, 2), B256, 0, stream>>>(Wkvb, 1024, Wp0t, 1024, 1024, nullptr, Wkv0c, 256, 0, 0);
  k_gemm<<<dim3(16, 4), B256, 0, stream>>>(Wkvb, 1024, Wp1t, 1024, 1024, nullptr, Wkv1c, 512, 0, 0);

  k_gemm<<<dim3(BT/128, 8), B256, 0, stream>>>(qb, 1024, Wqb, 1024, 1024, bq, Qb, 1024, 0, 0);
  k_attn2p<<<dim3(BT/128*8), B512, 0, stream>>>(x0b, x1b, x2b, Wkv0c, Wkv1c, Wkvb,
                                                bc0, bc1, bc2, Qb, ctxb, wacc);
  k_gemm<<<dim3(BT/128, 8), B256, 0, stream>>>(ctxb, 1024, Wob, 1024, 1024, bo, aob, 1024, 0, 0);
  k_ln<<<dim3(BT), B256, 0, stream>>>(aob, nullptr, g1, be1, f1b, nullptr);

  for (int c = 0; c < 4; ++c){
    const u16* fa = f1b + (size_t)c*8192*1024;
    k_gemm<<<dim3(64, 32), B256, 0, stream>>>(fa, 1024, W1b, 1024, 1024, b1, ff1c, 4096, 0, 1);
    k_gemm<<<dim3(64, 8),  B256, 0, stream>>>(ff1c, 4096, W2b, 4096, 4096, b2,
                                              ff2b + (size_t)c*8192*1024, 1024, 0, 0);
  }
  float* outf = (float*)d_out;
  k_ln<<<dim3(BT), B256, 0, stream>>>(ff2b, f1b, g2, be2, nullptr, outf);
  k_copyf<<<dim3(384), B256, 0, stream>>>(wacc, outf + (size_t)BT*1024, BT*3);
}